// Round 3
// baseline (1152.823 us; speedup 1.0000x reference)
//
#include <hip/hip_runtime.h>
#include <hip/hip_bf16.h>

// Problem constants (match reference)
#define NUM_C 37
#define TILE 256
// log(1/0.99) and log(0.99) as fp32
#define LOG_INV_BETA 0.010050336f
#define LOG_BETA    (-0.010050336f)
#define FLT_MAX_SAT 3.402823466e+38f

// ws layout (floats): [0..36] counts, [37] S (scaled focal sum), [38] E (max weight exponent)

// Bit-level finite scrub: nan/inf -> sat. Integer compare -- cannot be folded
// away by -ffinite-math-only (float isfinite() can be).
__device__ __forceinline__ float finite_scrub(float v, float sat) {
    unsigned u = __float_as_uint(v);
    if ((u & 0x7f800000u) == 0x7f800000u) return sat;  // exp all-ones: inf or nan
    return v;
}

__global__ void hist_kernel(const int* __restrict__ target, float* __restrict__ counts, int n) {
    __shared__ unsigned int h[NUM_C];
    for (int j = threadIdx.x; j < NUM_C; j += blockDim.x) h[j] = 0u;
    __syncthreads();

    const int4* t4 = (const int4*)target;
    int n4 = n >> 2;
    int stride = gridDim.x * blockDim.x;
    for (int i = blockIdx.x * blockDim.x + threadIdx.x; i < n4; i += stride) {
        int4 v = t4[i];
        // bounds-guard every index: an out-of-range class must never corrupt LDS
        if ((unsigned)v.x < NUM_C) atomicAdd(&h[v.x], 1u);
        if ((unsigned)v.y < NUM_C) atomicAdd(&h[v.y], 1u);
        if ((unsigned)v.z < NUM_C) atomicAdd(&h[v.z], 1u);
        if ((unsigned)v.w < NUM_C) atomicAdd(&h[v.w], 1u);
    }
    for (int i = (n4 << 2) + blockIdx.x * blockDim.x + threadIdx.x; i < n; i += stride) {
        int t = target[i];
        if ((unsigned)t < NUM_C) atomicAdd(&h[t], 1u);
    }
    __syncthreads();
    for (int j = threadIdx.x; j < NUM_C; j += blockDim.x)
        if (h[j]) atomicAdd(&counts[j], (float)h[j]);
}

// One wave: E = max_c counts[c] * log(1/beta)  -> ws[38]
__global__ void prep_kernel(float* __restrict__ ws) {
    int c = threadIdx.x;  // 64 threads
    float v = (c < NUM_C) ? ws[c] : 0.0f;
#pragma unroll
    for (int off = 32; off > 0; off >>= 1) v = fmaxf(v, __shfl_xor(v, off, 64));
    if (c == 0) ws[NUM_C + 1] = v * LOG_INV_BETA;
}

__global__ __launch_bounds__(TILE, 1) void focal_main(const float* __restrict__ logits,
                                                      const int* __restrict__ target,
                                                      float* __restrict__ ws,
                                                      int n) {
    __shared__ float sm[TILE * NUM_C];   // 37,888 B
    __shared__ float warp_part[TILE / 64];

    const float* counts = ws;
    float* S_sum = ws + NUM_C;
    const float E = ws[NUM_C + 1];       // max weight exponent

    int block_base = blockIdx.x * TILE;

    // ---- stage tile to LDS, coalesced float4 ----
    if (block_base + TILE <= n) {
        const float4* src = (const float4*)(logits + (size_t)block_base * NUM_C);
        float4* dst = (float4*)sm;
        const int nvec = TILE * NUM_C / 4;  // 2368
        for (int k = threadIdx.x; k < nvec; k += blockDim.x) dst[k] = src[k];
    } else {
        int rem = (n - block_base) * NUM_C;
        const float* src = logits + (size_t)block_base * NUM_C;
        for (int k = threadIdx.x; k < rem; k += blockDim.x) sm[k] = src[k];
    }
    __syncthreads();

    // ---- per-thread sample ----
    float local = 0.0f;
    int i = block_base + threadIdx.x;
    if (i < n) {
        const float* row = sm + threadIdx.x * NUM_C;  // stride 37 (==5 mod 32): conflict-free
        float r[NUM_C];
#pragma unroll
        for (int j = 0; j < NUM_C; ++j) r[j] = row[j];
        float m = r[0];
#pragma unroll
        for (int j = 1; j < NUM_C; ++j) m = fmaxf(m, r[j]);
        float s = 0.0f;
#pragma unroll
        for (int j = 0; j < NUM_C; ++j) s += expf(r[j] - m);
        int t = target[i];
        if ((unsigned)t >= NUM_C) t = 0;      // bounds-guard LDS/counts indexing
        float xt = row[t];
        float ce = logf(s) + m - xt;          // -log_softmax at target, > 0
        float pt = expf(-ce);
        // scaled weight exponent: counts[t]*log(1/beta) - E. Mathematically <= 0
        // (E is the max); clamp kills fp rounding or garbage-E positives.
        float ex = fmaf(counts[t], LOG_INV_BETA, -E);
        ex = fminf(ex, 0.0f);
        float w  = expf(ex);                  // in (0, 1]
        float om = 1.0f - pt;
        local = om * om * ce * w;             // ALPHA=1, GAMMA=2
        local = fminf(fmaxf(local, 0.0f), 1e30f);  // provably finite contribution
    }

    // ---- reduce: wave shuffle, LDS across 4 waves, one atomic/block ----
#pragma unroll
    for (int off = 32; off > 0; off >>= 1) local += __shfl_down(local, off, 64);
    if ((threadIdx.x & 63) == 0) warp_part[threadIdx.x >> 6] = local;
    __syncthreads();
    if (threadIdx.x == 0) {
        float blk = warp_part[0] + warp_part[1] + warp_part[2] + warp_part[3];
        atomicAdd(S_sum, blk);
    }
}

__global__ void finalize_kernel(const float* __restrict__ ws, float* __restrict__ out, int n) {
    int c = threadIdx.x;  // one wave
    float cnt = (c < NUM_C) ? ws[c] : 0.0f;
    float total = cnt;
#pragma unroll
    for (int off = 32; off > 0; off >>= 1) total += __shfl_xor(total, off, 64);
    total = fmaxf(total, 1.0f);
    // 1/class_weights[c] = beta^(counts[c]/total)
    float term = (c < NUM_C) ? expf((cnt / total) * LOG_BETA) : 0.0f;
    float s = term;
#pragma unroll
    for (int off = 32; off > 0; off >>= 1) s += __shfl_xor(s, off, 64);
    if (c == 0) {
        float S = finite_scrub(ws[NUM_C], 1e30f);      // scaled focal sum, >= 0
        float E = finite_scrub(ws[NUM_C + 1], 1e6f);   // max weight exponent
        E = fminf(fmaxf(E, 0.0f), 1e6f);
        // result = exp(E) * (S/n) * (s/NUM_C), computed in log space.
        float log_result = E + logf(fmaxf(S, 1e-38f) / (float)n)
                             + logf(fmaxf(s, 1e-38f) / (float)NUM_C);
        // Saturate BEFORE exp: expf(88) = 1.65e38 < FLT_MAX (finite).
        float v = expf(fminf(log_result, 88.0f));
        if (log_result < -103.0f) v = 0.0f;
        // Bit-level scrub: under NO circumstances store inf/nan.
        v = finite_scrub(v, FLT_MAX_SAT);
        v = fminf(fmaxf(v, 0.0f), FLT_MAX_SAT);
        out[0] = v;
    }
}

extern "C" void kernel_launch(void* const* d_in, const int* in_sizes, int n_in,
                              void* d_out, int out_size, void* d_ws, size_t ws_size,
                              hipStream_t stream) {
    const float* logits = (const float*)d_in[0];
    const int* target   = (const int*)d_in[1];
    float* out          = (float*)d_out;
    float* ws           = (float*)d_ws;
    int n = in_sizes[1];  // number of samples

    // zero counts[37] + S + E
    hipMemsetAsync(d_ws, 0, (NUM_C + 2) * sizeof(float), stream);

    hist_kernel<<<256, 256, 0, stream>>>(target, ws, n);
    prep_kernel<<<1, 64, 0, stream>>>(ws);

    int nblocks = (n + TILE - 1) / TILE;  // 16384
    focal_main<<<nblocks, TILE, 0, stream>>>(logits, target, ws, n);

    finalize_kernel<<<1, 64, 0, stream>>>(ws, out, n);
}

// Round 4
// 789.831 us; speedup vs baseline: 1.4596x; 1.4596x over previous
//
#include <hip/hip_runtime.h>
#include <hip/hip_bf16.h>

// Problem constants (match reference)
#define NUM_C 37
#define WTILE 64                    // samples per block = one wave
#define LOG_INV_BETA 0.010050336f
#define LOG_BETA    (-0.010050336f)
#define FLT_MAX_SAT 3.402823466e+38f

// Partial-sum slots: spread same-address atomic traffic over 64 lines
#define NSLOT 64
#define SLOT_STRIDE 16              // floats -> 64 B apart
// ws float layout: [0..36] counts, [37] E, [64 .. 64+NSLOT*16) partial slots
#define WS_E 37
#define WS_SLOTS 64
#define WS_TOTAL (WS_SLOTS + NSLOT * SLOT_STRIDE)   // 1088 floats

// Bit-level finite scrub (integer compare -- survives -ffinite-math-only)
__device__ __forceinline__ float finite_scrub(float v, float sat) {
    unsigned u = __float_as_uint(v);
    if ((u & 0x7f800000u) == 0x7f800000u) return sat;
    return v;
}

__global__ void hist_kernel(const int* __restrict__ target, float* __restrict__ counts, int n) {
    __shared__ unsigned int h[NUM_C];
    for (int j = threadIdx.x; j < NUM_C; j += blockDim.x) h[j] = 0u;
    __syncthreads();

    const int4* t4 = (const int4*)target;
    int n4 = n >> 2;
    int stride = gridDim.x * blockDim.x;
    for (int i = blockIdx.x * blockDim.x + threadIdx.x; i < n4; i += stride) {
        int4 v = t4[i];
        if ((unsigned)v.x < NUM_C) atomicAdd(&h[v.x], 1u);
        if ((unsigned)v.y < NUM_C) atomicAdd(&h[v.y], 1u);
        if ((unsigned)v.z < NUM_C) atomicAdd(&h[v.z], 1u);
        if ((unsigned)v.w < NUM_C) atomicAdd(&h[v.w], 1u);
    }
    for (int i = (n4 << 2) + blockIdx.x * blockDim.x + threadIdx.x; i < n; i += stride) {
        int t = target[i];
        if ((unsigned)t < NUM_C) atomicAdd(&h[t], 1u);
    }
    __syncthreads();
    for (int j = threadIdx.x; j < NUM_C; j += blockDim.x)
        if (h[j]) atomicAdd(&counts[j], (float)h[j]);
}

// One wave: E = max_c counts[c] * log(1/beta) -> ws[WS_E]
__global__ void prep_kernel(float* __restrict__ ws) {
    int c = threadIdx.x;
    float v = (c < NUM_C) ? ws[c] : 0.0f;
#pragma unroll
    for (int off = 32; off > 0; off >>= 1) v = fmaxf(v, __shfl_xor(v, off, 64));
    if (c == 0) ws[WS_E] = v * LOG_INV_BETA;
}

// Single-wave blocks: 64 samples/block, async global->LDS staging, no
// inter-wave barriers, 16 blocks/CU (LDS-capped at 9472 B/block).
__global__ __launch_bounds__(WTILE) void focal_main(const float* __restrict__ logits,
                                                    const int* __restrict__ target,
                                                    float* __restrict__ ws,
                                                    int n) {
    __shared__ float sm[WTILE * NUM_C];   // 2368 floats = 9472 B (16B-aligned tile)
    const int lane = threadIdx.x;
    const float E = ws[WS_E];

    long long base = (long long)blockIdx.x * WTILE;
    const float* src = logits + base * NUM_C;

    if (base + WTILE <= n) {
        // 9 rounds x (64 lanes x 16B) + 1 round x (64 lanes x 4B) = 9472 B,
        // contiguous lane-order: LDS dest = uniform base + lane*size (HW rule).
#pragma unroll
        for (int r = 0; r < 9; ++r) {
            __builtin_amdgcn_global_load_lds(
                (const __attribute__((address_space(1))) unsigned int*)(src + r * 256 + lane * 4),
                (__attribute__((address_space(3))) unsigned int*)((char*)sm + r * 1024),
                16, 0, 0);
        }
        __builtin_amdgcn_global_load_lds(
            (const __attribute__((address_space(1))) unsigned int*)(src + 9 * 256 + lane),
            (__attribute__((address_space(3))) unsigned int*)((char*)sm + 9 * 1024),
            4, 0, 0);
    } else {
        int rem = (int)((long long)n - base) * NUM_C;
        for (int k = lane; k < rem; k += WTILE) sm[k] = src[k];
    }
    __syncthreads();   // single wave: compiles to waitcnt, no cross-wave stall

    float local = 0.0f;
    long long i = base + lane;
    if (i < n) {
        const float* row = sm + lane * NUM_C;  // dword stride 37 == 5 mod 32: 2-way max (free)
        float r[NUM_C];
#pragma unroll
        for (int j = 0; j < NUM_C; ++j) r[j] = row[j];
        float m = r[0];
#pragma unroll
        for (int j = 1; j < NUM_C; ++j) m = fmaxf(m, r[j]);
        float s = 0.0f;
#pragma unroll
        for (int j = 0; j < NUM_C; ++j) s += __expf(r[j] - m);
        int t = target[i];
        if ((unsigned)t >= NUM_C) t = 0;      // bounds-guard
        float xt = row[t];
        float ce = __logf(s) + m - xt;        // -log_softmax at target
        float pt = __expf(-ce);
        float ex = fminf(fmaf(ws[t], LOG_INV_BETA, -E), 0.0f);  // scaled, <= 0
        float w  = __expf(ex);                // (0, 1]
        float om = 1.0f - pt;
        local = fminf(fmaxf(om * om * ce * w, 0.0f), 1e30f);  // finite by construction
    }

    // wave reduce, then ONE atomic per block into a spread slot (64B apart)
#pragma unroll
    for (int off = 32; off > 0; off >>= 1) local += __shfl_down(local, off, 64);
    if (lane == 0)
        atomicAdd(&ws[WS_SLOTS + (blockIdx.x & (NSLOT - 1)) * SLOT_STRIDE], local);
}

__global__ void finalize_kernel(const float* __restrict__ ws, float* __restrict__ out, int n) {
    int c = threadIdx.x;  // one wave, 64 lanes
    // sum the 64 partial slots
    float S = ws[WS_SLOTS + c * SLOT_STRIDE];
#pragma unroll
    for (int off = 32; off > 0; off >>= 1) S += __shfl_xor(S, off, 64);
    // class-weight mean
    float cnt = (c < NUM_C) ? ws[c] : 0.0f;
    float total = cnt;
#pragma unroll
    for (int off = 32; off > 0; off >>= 1) total += __shfl_xor(total, off, 64);
    total = fmaxf(total, 1.0f);
    float term = (c < NUM_C) ? __expf((cnt / total) * LOG_BETA) : 0.0f;
    float s = term;
#pragma unroll
    for (int off = 32; off > 0; off >>= 1) s += __shfl_xor(s, off, 64);
    if (c == 0) {
        float Sf = finite_scrub(S, 1e30f);
        float E  = finite_scrub(ws[WS_E], 1e6f);
        E = fminf(fmaxf(E, 0.0f), 1e6f);
        // result = exp(E) * (S/n) * (s/NUM_C), in log space, finite-saturated
        float log_result = E + __logf(fmaxf(Sf, 1e-38f) / (float)n)
                             + __logf(fmaxf(s, 1e-38f) / (float)NUM_C);
        float v = __expf(fminf(log_result, 88.0f));   // expf(88)=1.65e38 < FLT_MAX
        if (log_result < -103.0f) v = 0.0f;
        v = finite_scrub(v, FLT_MAX_SAT);
        v = fminf(fmaxf(v, 0.0f), FLT_MAX_SAT);
        out[0] = v;
    }
}

extern "C" void kernel_launch(void* const* d_in, const int* in_sizes, int n_in,
                              void* d_out, int out_size, void* d_ws, size_t ws_size,
                              hipStream_t stream) {
    const float* logits = (const float*)d_in[0];
    const int* target   = (const int*)d_in[1];
    float* out          = (float*)d_out;
    float* ws           = (float*)d_ws;
    int n = in_sizes[1];

    hipMemsetAsync(d_ws, 0, WS_TOTAL * sizeof(float), stream);

    hist_kernel<<<256, 256, 0, stream>>>(target, ws, n);
    prep_kernel<<<1, 64, 0, stream>>>(ws);

    int nblocks = (n + WTILE - 1) / WTILE;   // 65,536 single-wave blocks
    focal_main<<<nblocks, WTILE, 0, stream>>>(logits, target, ws, n);

    finalize_kernel<<<1, 64, 0, stream>>>(ws, out, n);
}

// Round 5
// 787.960 us; speedup vs baseline: 1.4630x; 1.0024x over previous
//
#include <hip/hip_runtime.h>
#include <hip/hip_bf16.h>

// Problem constants (match reference)
#define NUM_C 37
#define LOG_INV_BETA 0.010050336f
#define LOG_BETA    (-0.010050336f)
#define FLT_MAX_SAT 3.402823466e+38f

#define NBLK 4096                 // 16 blocks/CU target; each single-wave
#define NSLOT 32                  // spread copies for per-class global accumulators
#define SLOT_PITCH 40             // floats per slot copy (37 padded)
// ws float layout:
//   [64 .. 64+32*40)            counts slots
//   [1344 .. 1344+32*40)        P slots
#define WS_CNT 64
#define WS_P   (WS_CNT + NSLOT * SLOT_PITCH)      // 1344
#define WS_TOTAL (WS_P + NSLOT * SLOT_PITCH)      // 2624 floats

// Bit-level finite scrub (integer compare -- survives -ffinite-math-only)
__device__ __forceinline__ float finite_scrub(float v, float sat) {
    unsigned u = __float_as_uint(v);
    if ((u & 0x7f800000u) == 0x7f800000u) return sat;
    return v;
}

// Stage one full 64-sample tile (64*37 floats + 64 ints) via async global->LDS.
// 9 x width-16 rounds (9216 B) + 1 x width-4 round (256 B) + target width-4.
// LDS dest is wave-uniform base + lane*size (HW rule) -- layout is contiguous.
__device__ __forceinline__ void stage_tile_async(const float* __restrict__ src,
                                                 const int* __restrict__ tgt,
                                                 float* bufp, int* tbufp, int lane) {
#pragma unroll
    for (int r = 0; r < 9; ++r) {
        __builtin_amdgcn_global_load_lds(
            (const __attribute__((address_space(1))) unsigned int*)(src + r * 256 + lane * 4),
            (__attribute__((address_space(3))) unsigned int*)((char*)bufp + r * 1024),
            16, 0, 0);
    }
    __builtin_amdgcn_global_load_lds(
        (const __attribute__((address_space(1))) unsigned int*)(src + 2304 + lane),
        (__attribute__((address_space(3))) unsigned int*)((char*)bufp + 9216), 4, 0, 0);
    __builtin_amdgcn_global_load_lds(
        (const __attribute__((address_space(1))) unsigned int*)(tgt + lane),
        (__attribute__((address_space(3))) unsigned int*)tbufp, 4, 0, 0);
}

__device__ __forceinline__ void stage_tile_partial(const float* __restrict__ src,
                                                   const int* __restrict__ tgt,
                                                   float* bufp, int* tbufp,
                                                   int lane, int rem) {
    for (int k = lane; k < rem * NUM_C; k += 64) bufp[k] = src[k];
    if (lane < rem) tbufp[lane] = tgt[lane];
}

// Fused single pass: per-class P_c = sum over samples of (1-pt)^2*ce, and
// counts[c]. Weights are applied per-class in finalize (they only depend on
// the class), so no histogram pre-pass is needed.
__global__ __launch_bounds__(64) void fused_main(const float* __restrict__ logits,
                                                 const int* __restrict__ target,
                                                 float* __restrict__ ws,
                                                 int n) {
    __shared__ float buf[2][64 * NUM_C];   // 2 x 9472 B
    __shared__ int   tbuf[2][64];
    __shared__ float hP[NUM_C];
    __shared__ unsigned hC[NUM_C];

    const int lane = threadIdx.x;
    if (lane < NUM_C) { hP[lane] = 0.0f; hC[lane] = 0u; }   // single wave: in-order

    const int total_tiles = (n + 63) >> 6;
    int tile = blockIdx.x;
    int pb = 0;

    // prologue: stage first tile
    if (tile < total_tiles) {
        long long base = (long long)tile << 6;
        if (base + 64 <= n)
            stage_tile_async(logits + base * NUM_C, target + base, buf[0], tbuf[0], lane);
        else
            stage_tile_partial(logits + base * NUM_C, target + base, buf[0], tbuf[0],
                               lane, (int)(n - base));
    }

    while (tile < total_tiles) {
        int next = tile + gridDim.x;
        if (next < total_tiles) {
            long long nb = (long long)next << 6;
            if (nb + 64 <= n)
                stage_tile_async(logits + nb * NUM_C, target + nb, buf[pb ^ 1], tbuf[pb ^ 1], lane);
            else
                stage_tile_partial(logits + nb * NUM_C, target + nb, buf[pb ^ 1], tbuf[pb ^ 1],
                                   lane, (int)(n - nb));
            // wait for CURRENT tile only: next tile's 11 loads stay in flight.
            __asm__ __volatile__("s_waitcnt vmcnt(11) lgkmcnt(0)" ::: "memory");
        } else {
            __asm__ __volatile__("s_waitcnt vmcnt(0) lgkmcnt(0)" ::: "memory");
        }

        // ---- compute current tile ----
        long long base = (long long)tile << 6;
        int rem = (int)((n - base) < 64 ? (n - base) : 64);
        if (lane < rem) {
            const float* row = &buf[pb][lane * NUM_C];  // dword stride 37 == 5 mod 32: free
            float r[NUM_C];
#pragma unroll
            for (int j = 0; j < NUM_C; ++j) r[j] = row[j];
            float m = r[0];
#pragma unroll
            for (int j = 1; j < NUM_C; ++j) m = fmaxf(m, r[j]);
            float s = 0.0f;
#pragma unroll
            for (int j = 0; j < NUM_C; ++j) s += __expf(r[j] - m);
            int t = tbuf[pb][lane];
            if ((unsigned)t >= NUM_C) t = 0;            // bounds-guard
            float xt = row[t];                          // dynamic index -> LDS read
            float ce = __logf(s) + m - xt;              // -log_softmax at target
            float pt = __expf(-ce);
            float om = 1.0f - pt;
            float term = fminf(fmaxf(om * om * ce, 0.0f), 1e30f);  // finite, unweighted
            atomicAdd(&hP[t], term);                    // LDS fp atomic, ~2-way contention
            atomicAdd(&hC[t], 1u);
        }

        tile = next;
        pb ^= 1;
    }

    __syncthreads();   // single wave: just drains lgkmcnt for the LDS atomics
    if (lane < NUM_C) {
        int slot = blockIdx.x & (NSLOT - 1);
        atomicAdd(&ws[WS_CNT + slot * SLOT_PITCH + lane], (float)hC[lane]);
        atomicAdd(&ws[WS_P   + slot * SLOT_PITCH + lane], hP[lane]);
    }
}

__global__ void finalize_kernel(const float* __restrict__ ws, float* __restrict__ out, int n) {
    int c = threadIdx.x;  // one wave
    float cnt = 0.0f, P = 0.0f;
    if (c < NUM_C) {
#pragma unroll
        for (int sidx = 0; sidx < NSLOT; ++sidx) {
            cnt += ws[WS_CNT + sidx * SLOT_PITCH + c];
            P   += ws[WS_P   + sidx * SLOT_PITCH + c];
        }
    }
    // E = max_c cnt_c * log(1/beta)
    float e = (c < NUM_C) ? cnt * LOG_INV_BETA : 0.0f;
    float E = e;
#pragma unroll
    for (int off = 32; off > 0; off >>= 1) E = fmaxf(E, __shfl_xor(E, off, 64));
    // scaled weighted focal sum: S = sum_c P_c * exp(e_c - E)  (finite, each factor <= 1)
    float term = (c < NUM_C) ? P * __expf(fminf(e - E, 0.0f)) : 0.0f;
    float S = term;
#pragma unroll
    for (int off = 32; off > 0; off >>= 1) S += __shfl_xor(S, off, 64);
    // total and class-weight mean: mean_c beta^(cnt_c/total)
    float total = cnt;
#pragma unroll
    for (int off = 32; off > 0; off >>= 1) total += __shfl_xor(total, off, 64);
    total = fmaxf(total, 1.0f);
    float cw = (c < NUM_C) ? __expf((cnt / total) * LOG_BETA) : 0.0f;
    float s = cw;
#pragma unroll
    for (int off = 32; off > 0; off >>= 1) s += __shfl_xor(s, off, 64);
    if (c == 0) {
        float Sf = finite_scrub(S, 1e30f);
        float Ef = fminf(fmaxf(finite_scrub(E, 1e6f), 0.0f), 1e6f);
        // result = exp(E) * (S/n) * (s/NUM_C), in log space, finite-saturated
        float log_result = Ef + __logf(fmaxf(Sf, 1e-38f) / (float)n)
                              + __logf(fmaxf(s, 1e-38f) / (float)NUM_C);
        float v = __expf(fminf(log_result, 88.0f));   // expf(88)=1.65e38 < FLT_MAX
        if (log_result < -103.0f) v = 0.0f;
        v = finite_scrub(v, FLT_MAX_SAT);             // never store inf/nan
        v = fminf(fmaxf(v, 0.0f), FLT_MAX_SAT);
        out[0] = v;
    }
}

extern "C" void kernel_launch(void* const* d_in, const int* in_sizes, int n_in,
                              void* d_out, int out_size, void* d_ws, size_t ws_size,
                              hipStream_t stream) {
    const float* logits = (const float*)d_in[0];
    const int* target   = (const int*)d_in[1];
    float* out          = (float*)d_out;
    float* ws           = (float*)d_ws;
    int n = in_sizes[1];

    hipMemsetAsync(d_ws, 0, WS_TOTAL * sizeof(float), stream);

    int total_tiles = (n + 63) >> 6;
    int nblocks = total_tiles < NBLK ? total_tiles : NBLK;
    fused_main<<<nblocks, 64, 0, stream>>>(logits, target, ws, n);

    finalize_kernel<<<1, 64, 0, stream>>>(ws, out, n);
}